// Round 4
// baseline (4978.104 us; speedup 1.0000x reference)
//
#include <hip/hip_runtime.h>

typedef float f4 __attribute__((ext_vector_type(4)));

__device__ __forceinline__ float sigf(float x){ return 1.0f/(1.0f + __expf(-x)); }
// tanh(x) = 1 - 2/(e^{2x}+1); saturates cleanly to +-1 without NaN at extremes
__device__ __forceinline__ float tanhf_fast(float x){ float e = __expf(2.0f*x); return 1.0f - 2.0f/(e+1.0f); }
__device__ __forceinline__ f4 f4max(f4 a, f4 b){
  f4 r; r[0]=fmaxf(a[0],b[0]); r[1]=fmaxf(a[1],b[1]); r[2]=fmaxf(a[2],b[2]); r[3]=fmaxf(a[3],b[3]); return r;
}
#define D4(acc,wv,hv) acc = fmaf((wv)[0],(hv)[0],fmaf((wv)[1],(hv)[1],fmaf((wv)[2],(hv)[2],fmaf((wv)[3],(hv)[3],acc))))

// ---------------- embedding gather ----------------
__global__ void k_embed(const int* __restrict__ ids, const float* __restrict__ emb, float* __restrict__ x){
  int i = blockIdx.x*256 + threadIdx.x;          // < 1024*128
  x[i] = emb[(ids[i>>7]<<7) + (i&127)];
}

// ---------------- generic fp32 GEMM: C[M][N] = A[M][K] @ W[N][K]^T (+bias[n]) ----------------
__global__ __launch_bounds__(256) void k_gemm_bias(
    const float* __restrict__ A, const float* __restrict__ W, const float* __restrict__ bias,
    float* __restrict__ C, int N, int K){
  __shared__ float As[16][68];   // [k][m] transposed stage
  __shared__ float Ws[16][68];   // [k][n]
  int tid = threadIdx.x;
  int tr = tid>>4, tc = tid&15;
  int m0 = blockIdx.x<<6, n0 = blockIdx.y<<6;
  int rr = tid>>2, kq = (tid&3)<<2;
  const float* Ap = A + (size_t)(m0+rr)*K + kq;
  const float* Wp = W + (size_t)(n0+rr)*K + kq;
  float acc[4][4] = {};
  for (int k0 = 0; k0 < K; k0 += 16){
    float4 av = *(const float4*)(Ap + k0);
    float4 wv = *(const float4*)(Wp + k0);
    __syncthreads();
    As[kq+0][rr]=av.x; As[kq+1][rr]=av.y; As[kq+2][rr]=av.z; As[kq+3][rr]=av.w;
    Ws[kq+0][rr]=wv.x; Ws[kq+1][rr]=wv.y; Ws[kq+2][rr]=wv.z; Ws[kq+3][rr]=wv.w;
    __syncthreads();
    #pragma unroll
    for (int kk=0;kk<16;kk++){
      float4 a = *(const float4*)&As[kk][tr<<2];
      float4 b = *(const float4*)&Ws[kk][tc<<2];
      acc[0][0]=fmaf(a.x,b.x,acc[0][0]); acc[0][1]=fmaf(a.x,b.y,acc[0][1]);
      acc[0][2]=fmaf(a.x,b.z,acc[0][2]); acc[0][3]=fmaf(a.x,b.w,acc[0][3]);
      acc[1][0]=fmaf(a.y,b.x,acc[1][0]); acc[1][1]=fmaf(a.y,b.y,acc[1][1]);
      acc[1][2]=fmaf(a.y,b.z,acc[1][2]); acc[1][3]=fmaf(a.y,b.w,acc[1][3]);
      acc[2][0]=fmaf(a.z,b.x,acc[2][0]); acc[2][1]=fmaf(a.z,b.y,acc[2][1]);
      acc[2][2]=fmaf(a.z,b.z,acc[2][2]); acc[2][3]=fmaf(a.z,b.w,acc[2][3]);
      acc[3][0]=fmaf(a.w,b.x,acc[3][0]); acc[3][1]=fmaf(a.w,b.y,acc[3][1]);
      acc[3][2]=fmaf(a.w,b.z,acc[3][2]); acc[3][3]=fmaf(a.w,b.w,acc[3][3]);
    }
  }
  #pragma unroll
  for (int i=0;i<4;i++){
    int m = m0 + (tr<<2) + i;
    #pragma unroll
    for (int j=0;j<4;j++){
      int n = n0 + (tc<<2) + j;
      float v = acc[i][j];
      if (bias) v += bias[n];
      C[(size_t)m*N + n] = v;
    }
  }
}

// ---------------- persistent bidirectional LSTM layer ----------------
// grid = 32 (dir = bid/16, slice w = bid%16 owns hidden j in [16w,16w+16))
// Sync: DATA-AS-SIGNAL. h in (-1,1) strictly; sentinel 0x40404040 (=3.004) marks
// "not yet written". hbuf has 4 rotating slots per dir, pre-memset to sentinel.
// Producer wave0 stores h with sc0 sc1 (straight to coherence point); every consumer
// thread polls exactly its own 16 float4s and fma's from registers. No atomics, no
// fences, no L2 inv/wb, no LDS h-staging. Slot reset happens 2 steps later by the
// producing lane (same-wave same-address coherence orders reset < rewrite; skew<=2
// proves no reader can still need the slot). hcat staged in LDS, dumped at the end.
__global__ __launch_bounds__(1024) void k_lstm(
    const float* __restrict__ gx,    // [1024 m][2048]  n = dir*1024 + q*256 + j
    const float* __restrict__ whh,   // [2][1024][256]
    float* __restrict__ hcat,        // [1024 m][512]   out: dir*256 + j
    float* __restrict__ hbuf){       // [2 dir][4 slot][4 b][256 j], pre-set 0x40
  int bid = blockIdx.x;
  int dir = bid >> 4;
  int w   = bid & 15;
  int j0  = w << 4;
  int tid = threadIdx.x;
  int kc  = tid & 15;
  int r   = tid >> 4;
  int grow = ((r>>4)<<8) + j0 + (r&15);   // gate row in [0,1024)

  // W_hh slice: 16 floats as 4 f4s
  const f4* wp4 = (const f4*)(whh + (size_t)(dir*1024 + grow)*256 + (kc<<4));
  f4 w40 = wp4[0], w41 = wp4[1], w42 = wp4[2], w43 = wp4[3];

  __shared__ float hist[16384];        // h history for hcat: [s][b*16+j2]
  __shared__ float glds[2][4][64];     // gate sums, double-buffered by s&1

  float* hb = hbuf + dir*4096;
  float c_reg = 0.0f;
  const float sent = __uint_as_float(0x40404040u);

  for (int s = 0; s < 256; s++){
    // gx prefetch for the nonlinearity lanes (hidden under poll+dot)
    float gxv0=0.f, gxv1=0.f, gxv2=0.f, gxv3=0.f;
    if (tid < 64){
      int b = tid>>4, j2 = tid&15;
      const float* gp = gx + (size_t)((b<<8) + (dir ? 255-s : s))*2048 + dir*1024 + j0 + j2;
      gxv0 = gp[0]; gxv1 = gp[256]; gxv2 = gp[512]; gxv3 = gp[768];
    }
    float a0=0.f, a1=0.f, a2=0.f, a3=0.f;
    if (s){
      const float* base = hb + (((s-1)&3)<<10) + (kc<<4);
      f4 h00,h01,h02,h03,h10,h11,h12,h13,h20,h21,h22,h23,h30,h31,h32,h33;
      for(;;){
        asm volatile(
          "global_load_dwordx4 %[y0], %[p], off sc0 sc1\n\t"
          "global_load_dwordx4 %[y1], %[p], off offset:16 sc0 sc1\n\t"
          "global_load_dwordx4 %[y2], %[p], off offset:32 sc0 sc1\n\t"
          "global_load_dwordx4 %[y3], %[p], off offset:48 sc0 sc1\n\t"
          "global_load_dwordx4 %[y4], %[p], off offset:1024 sc0 sc1\n\t"
          "global_load_dwordx4 %[y5], %[p], off offset:1040 sc0 sc1\n\t"
          "global_load_dwordx4 %[y6], %[p], off offset:1056 sc0 sc1\n\t"
          "global_load_dwordx4 %[y7], %[p], off offset:1072 sc0 sc1\n\t"
          "global_load_dwordx4 %[y8], %[p], off offset:2048 sc0 sc1\n\t"
          "global_load_dwordx4 %[y9], %[p], off offset:2064 sc0 sc1\n\t"
          "global_load_dwordx4 %[yA], %[p], off offset:2080 sc0 sc1\n\t"
          "global_load_dwordx4 %[yB], %[p], off offset:2096 sc0 sc1\n\t"
          "global_load_dwordx4 %[yC], %[p], off offset:3072 sc0 sc1\n\t"
          "global_load_dwordx4 %[yD], %[p], off offset:3088 sc0 sc1\n\t"
          "global_load_dwordx4 %[yE], %[p], off offset:3104 sc0 sc1\n\t"
          "global_load_dwordx4 %[yF], %[p], off offset:3120 sc0 sc1\n\t"
          "s_waitcnt vmcnt(0)"
          : [y0]"=&v"(h00),[y1]"=&v"(h01),[y2]"=&v"(h02),[y3]"=&v"(h03),
            [y4]"=&v"(h10),[y5]"=&v"(h11),[y6]"=&v"(h12),[y7]"=&v"(h13),
            [y8]"=&v"(h20),[y9]"=&v"(h21),[yA]"=&v"(h22),[yB]"=&v"(h23),
            [yC]"=&v"(h30),[yD]"=&v"(h31),[yE]"=&v"(h32),[yF]"=&v"(h33)
          : [p]"v"(base) : "memory");
        f4 m4 = f4max(f4max(f4max(h00,h01),f4max(h02,h03)),
                      f4max(f4max(h10,h11),f4max(h12,h13)));
        m4 = f4max(m4, f4max(f4max(f4max(h20,h21),f4max(h22,h23)),
                             f4max(f4max(h30,h31),f4max(h32,h33))));
        float mx = fmaxf(fmaxf(m4[0],m4[1]), fmaxf(m4[2],m4[3]));
        if (mx < 2.0f) break;    // all 64 operands are real h values
      }
      D4(a0,w40,h00); D4(a0,w41,h01); D4(a0,w42,h02); D4(a0,w43,h03);
      D4(a1,w40,h10); D4(a1,w41,h11); D4(a1,w42,h12); D4(a1,w43,h13);
      D4(a2,w40,h20); D4(a2,w41,h21); D4(a2,w42,h22); D4(a2,w43,h23);
      D4(a3,w40,h30); D4(a3,w41,h31); D4(a3,w42,h32); D4(a3,w43,h33);
    }
    // reduce over the 16 kc lanes (low 4 bits of lane id)
    #pragma unroll
    for (int m=1; m<16; m<<=1){
      a0 += __shfl_xor(a0, m, 64);
      a1 += __shfl_xor(a1, m, 64);
      a2 += __shfl_xor(a2, m, 64);
      a3 += __shfl_xor(a3, m, 64);
    }
    if (kc == 0){
      glds[s&1][0][r]=a0; glds[s&1][1][r]=a1; glds[s&1][2][r]=a2; glds[s&1][3][r]=a3;
    }
    __syncthreads();
    if (tid < 64){            // wave 0: nonlinearity + publish (+ lazy slot reset)
      int b = tid>>4, j2 = tid&15;
      float gi = gxv0 + glds[s&1][b][ 0+j2];
      float gf = gxv1 + glds[s&1][b][16+j2];
      float gg = gxv2 + glds[s&1][b][32+j2];
      float go = gxv3 + glds[s&1][b][48+j2];
      c_reg   = sigf(gf)*c_reg + sigf(gi)*tanhf_fast(gg);
      float h = sigf(go)*tanhf_fast(c_reg);
      hist[(s<<6) + tid] = h;
      float* dst = hb + ((s&3)<<10) + (b<<8) + j0 + j2;
      asm volatile("global_store_dword %[p], %[v], off sc0 sc1"
                   :: [p]"v"(dst), [v]"v"(h) : "memory");
      if (s >= 2){
        float* rst = hb + (((s-2)&3)<<10) + (b<<8) + j0 + j2;
        asm volatile("global_store_dword %[p], %[v], off sc0 sc1"
                     :: [p]"v"(rst), [v]"v"(sent) : "memory");
      }
    }
    // no trailing barrier: other waves may run ahead into the next poll;
    // glds is double-buffered and hist/c_reg are wave0-private.
  }
  __syncthreads();
  // dump h history to hcat (once)
  for (int i = tid; i < 16384; i += 1024){
    int s = i>>6, lane = i&63, b = lane>>4, j2 = lane&15;
    int t = dir ? 255-s : s;
    hcat[(size_t)((b<<8)+t)*512 + (dir<<8) + j0 + j2] = hist[i];
  }
}

// ---------------- fused additive attention + softmax + ctx + classifier ----------------
__global__ __launch_bounds__(256) void k_attn(
    const float* __restrict__ q, const float* __restrict__ kmat,
    const float* __restrict__ h, const float* __restrict__ v,
    const float* __restrict__ clsW, const float* __restrict__ clsb,
    float* __restrict__ out){
  int bt = blockIdx.x;           // b*256 + t
  int b  = bt >> 8;
  int tid = threadIdx.x;
  __shared__ float q_s[512], v_s[512], p_s[256], red[8], ctx_s[512], part[240];
  *(float2*)&q_s[tid<<1] = *(const float2*)&q[(size_t)bt*512 + (tid<<1)];
  *(float2*)&v_s[tid<<1] = *(const float2*)&v[tid<<1];
  __syncthreads();
  const float* kp = kmat + (size_t)((b<<8) + tid)*512;
  float sc = 0.f;
  for (int d=0; d<512; d+=4){
    float4 kv = *(const float4*)&kp[d];
    sc += v_s[d+0]*tanhf_fast(q_s[d+0]+kv.x)
        + v_s[d+1]*tanhf_fast(q_s[d+1]+kv.y)
        + v_s[d+2]*tanhf_fast(q_s[d+2]+kv.z)
        + v_s[d+3]*tanhf_fast(q_s[d+3]+kv.w);
  }
  int wv = tid>>6, lane = tid&63;
  float m = sc;
  #pragma unroll
  for (int o=1;o<64;o<<=1) m = fmaxf(m, __shfl_xor(m,o,64));
  if (lane==0) red[wv] = m;
  __syncthreads();
  m = fmaxf(fmaxf(red[0],red[1]), fmaxf(red[2],red[3]));
  float p = __expf(sc - m);
  p_s[tid] = p;
  float sum = p;
  #pragma unroll
  for (int o=1;o<64;o<<=1) sum += __shfl_xor(sum,o,64);
  if (lane==0) red[4+wv] = sum;
  __syncthreads();
  float inv = 1.0f/(red[4]+red[5]+red[6]+red[7]);
  float cx=0.f, cy=0.f;
  for (int s2=0; s2<256; s2++){
    float pw = p_s[s2];
    float2 hv = *(const float2*)&h[(size_t)((b<<8)+s2)*512 + (tid<<1)];
    cx = fmaf(pw, hv.x, cx); cy = fmaf(pw, hv.y, cy);
  }
  ctx_s[tid<<1] = cx*inv; ctx_s[(tid<<1)+1] = cy*inv;
  __syncthreads();
  if (tid < 240){
    int c = tid>>4, ch = tid&15;
    const float* wrow = clsW + (size_t)c*512 + (ch<<5);
    const float* cc = &ctx_s[ch<<5];
    float acc = 0.f;
    #pragma unroll
    for (int i=0;i<32;i++) acc = fmaf(wrow[i], cc[i], acc);
    part[tid] = acc;
  }
  __syncthreads();
  if (tid < 15){
    float o = clsb[tid];
    #pragma unroll
    for (int i=0;i<16;i++) o += part[(tid<<4)+i];
    out[(size_t)bt*15 + tid] = o;
  }
}

extern "C" void kernel_launch(void* const* d_in, const int* in_sizes, int n_in,
                              void* d_out, int out_size, void* d_ws, size_t ws_size,
                              hipStream_t stream){
  (void)in_sizes; (void)n_in; (void)out_size; (void)ws_size;
  const int*   ids    = (const int*)  d_in[0];
  const float* emb    = (const float*)d_in[1];
  const float* w_ih0  = (const float*)d_in[2];
  const float* w_hh0  = (const float*)d_in[3];
  const float* b0     = (const float*)d_in[4];
  const float* w_ih   = (const float*)d_in[5];
  const float* w_hh   = (const float*)d_in[6];
  const float* b      = (const float*)d_in[7];
  const float* attn_W = (const float*)d_in[8];
  const float* attn_U = (const float*)d_in[9];
  const float* attn_v = (const float*)d_in[10];
  const float* cls_W  = (const float*)d_in[11];
  const float* cls_b  = (const float*)d_in[12];
  float* out = (float*)d_out;

  float* ws   = (float*)d_ws;
  float* x    = ws;                  // 131072
  float* gx   = x  + 131072;         // 2097152 (1024 x 2048)
  float* hA   = gx + 2097152;        // 524288  (1024 x 512)
  float* hB   = hA + 524288;         // 524288
  float* hbuf = hB + 524288;         // 3 layers x 8192 floats ([2][4][4][256])
  float* qb   = gx;                  // reuse gx after recurrences done
  float* kb   = gx + 524288;

  // sentinel-fill the h exchange buffers (0x40404040 = 3.004f, unreachable by |h|<=1)
  hipMemsetAsync(hbuf, 0x40, 3*8192*sizeof(float), stream);
  k_embed<<<512, 256, 0, stream>>>(ids, emb, x);

  dim3 gBig(16, 32);   // M=1024, N=2048
  dim3 gQK(16, 8);     // M=1024, N=512

  // layer 0
  k_gemm_bias<<<gBig, 256, 0, stream>>>(x, w_ih0, b0, gx, 2048, 128);
  k_lstm<<<32, 1024, 0, stream>>>(gx, w_hh0, hA, hbuf + 0*8192);
  // layer 1
  k_gemm_bias<<<gBig, 256, 0, stream>>>(hA, w_ih, b, gx, 2048, 512);
  k_lstm<<<32, 1024, 0, stream>>>(gx, w_hh, hB, hbuf + 1*8192);
  // layer 2
  k_gemm_bias<<<gBig, 256, 0, stream>>>(hB, w_ih + 2048*512, b + 2048, gx, 2048, 512);
  k_lstm<<<32, 1024, 0, stream>>>(gx, w_hh + 2048*256, hA, hbuf + 2*8192);
  // attention projections
  k_gemm_bias<<<gQK, 256, 0, stream>>>(hA, attn_W, nullptr, qb, 512, 512);
  k_gemm_bias<<<gQK, 256, 0, stream>>>(hA, attn_U, nullptr, kb, 512, 512);
  // fused scores/softmax/ctx/classifier
  k_attn<<<1024, 256, 0, stream>>>(qb, kb, hA, attn_v, cls_W, cls_b, out);
}

// Round 5
// 2129.685 us; speedup vs baseline: 2.3375x; 2.3375x over previous
//
#include <hip/hip_runtime.h>

typedef float f4 __attribute__((ext_vector_type(4)));

__device__ __forceinline__ float sigf(float x){ return 1.0f/(1.0f + __expf(-x)); }
// tanh(x) = 1 - 2/(e^{2x}+1); saturates cleanly to +-1 without NaN at extremes
__device__ __forceinline__ float tanhf_fast(float x){ float e = __expf(2.0f*x); return 1.0f - 2.0f/(e+1.0f); }

// DPP 16-lane butterfly add stage (pure VALU, no DS pipe):
// 0xB1 quad_perm[1,0,3,2]=xor1, 0x4E quad_perm[2,3,0,1]=xor2,
// 0x141 row_half_mirror (i^7 pairing across quads), 0x140 row_mirror (i^15)
#define DPPADD(x, ctrl) x += __int_as_float(__builtin_amdgcn_mov_dpp(__float_as_int(x), ctrl, 0xf, 0xf, false))
#define DPPRED16(x) do{ DPPADD(x,0xB1); DPPADD(x,0x4E); DPPADD(x,0x141); DPPADD(x,0x140); }while(0)

// swizzled LDS word for h[k][b]: 8k + 4*((k>>4)&7) + b  (dot read = b128, <=2-way banks)
__device__ __forceinline__ int hswz(int k){ return (k<<3) + (((k>>4)&7)<<2); }

// ---------------- embedding gather ----------------
__global__ void k_embed(const int* __restrict__ ids, const float* __restrict__ emb, float* __restrict__ x){
  int i = blockIdx.x*256 + threadIdx.x;          // < 1024*128
  x[i] = emb[(ids[i>>7]<<7) + (i&127)];
}

// ---------------- generic fp32 GEMM: C[M][N] = A[M][K] @ W[N][K]^T (+bias[n]) ----------------
__global__ __launch_bounds__(256) void k_gemm_bias(
    const float* __restrict__ A, const float* __restrict__ W, const float* __restrict__ bias,
    float* __restrict__ C, int N, int K){
  __shared__ float As[16][68];   // [k][m] transposed stage
  __shared__ float Ws[16][68];   // [k][n]
  int tid = threadIdx.x;
  int tr = tid>>4, tc = tid&15;
  int m0 = blockIdx.x<<6, n0 = blockIdx.y<<6;
  int rr = tid>>2, kq = (tid&3)<<2;
  const float* Ap = A + (size_t)(m0+rr)*K + kq;
  const float* Wp = W + (size_t)(n0+rr)*K + kq;
  float acc[4][4] = {};
  for (int k0 = 0; k0 < K; k0 += 16){
    float4 av = *(const float4*)(Ap + k0);
    float4 wv = *(const float4*)(Wp + k0);
    __syncthreads();
    As[kq+0][rr]=av.x; As[kq+1][rr]=av.y; As[kq+2][rr]=av.z; As[kq+3][rr]=av.w;
    Ws[kq+0][rr]=wv.x; Ws[kq+1][rr]=wv.y; Ws[kq+2][rr]=wv.z; Ws[kq+3][rr]=wv.w;
    __syncthreads();
    #pragma unroll
    for (int kk=0;kk<16;kk++){
      float4 a = *(const float4*)&As[kk][tr<<2];
      float4 b = *(const float4*)&Ws[kk][tc<<2];
      acc[0][0]=fmaf(a.x,b.x,acc[0][0]); acc[0][1]=fmaf(a.x,b.y,acc[0][1]);
      acc[0][2]=fmaf(a.x,b.z,acc[0][2]); acc[0][3]=fmaf(a.x,b.w,acc[0][3]);
      acc[1][0]=fmaf(a.y,b.x,acc[1][0]); acc[1][1]=fmaf(a.y,b.y,acc[1][1]);
      acc[1][2]=fmaf(a.y,b.z,acc[1][2]); acc[1][3]=fmaf(a.y,b.w,acc[1][3]);
      acc[2][0]=fmaf(a.z,b.x,acc[2][0]); acc[2][1]=fmaf(a.z,b.y,acc[2][1]);
      acc[2][2]=fmaf(a.z,b.z,acc[2][2]); acc[2][3]=fmaf(a.z,b.w,acc[2][3]);
      acc[3][0]=fmaf(a.w,b.x,acc[3][0]); acc[3][1]=fmaf(a.w,b.y,acc[3][1]);
      acc[3][2]=fmaf(a.w,b.z,acc[3][2]); acc[3][3]=fmaf(a.w,b.w,acc[3][3]);
    }
  }
  #pragma unroll
  for (int i=0;i<4;i++){
    int m = m0 + (tr<<2) + i;
    #pragma unroll
    for (int j=0;j<4;j++){
      int n = n0 + (tc<<2) + j;
      float v = acc[i][j];
      if (bias) v += bias[n];
      C[(size_t)m*N + n] = v;
    }
  }
}

// ---------------- persistent bidirectional LSTM layer ----------------
// grid = 32 (dir = bid/16, slice w = bid%16 owns hidden j in [16w,16w+16))
// Sync: sentinel data-as-signal (no atomics/fences), but with MINIMAL poll traffic:
// hbuf slot layout is [256 k][4 b] (word k*4+b); wave W polls ONLY its 256B chunk
// (1 dword/lane, k in [16W,16W+16)) and stages it to swizzled LDS once valid.
// Dot reads ds_read_b128 = h[k][b0..3] (4-row broadcast, <=2-way banks); the
// 16-lane reduction is a DPP butterfly (VALU, zero DS ops). Single-buffered LDS
// is safe: staging for step s+1 can only begin after ALL WGs produced step s,
// which implies every wave in this WG passed bar2(s) (finished dot(s)).
__global__ __launch_bounds__(1024) void k_lstm(
    const float* __restrict__ gx,    // [1024 m][2048]  n = dir*1024 + q*256 + j
    const float* __restrict__ whh,   // [2][1024][256]
    float* __restrict__ hcat,        // [1024 m][512]   out: dir*256 + j
    float* __restrict__ hbuf){       // [2 dir][4 slot][256 k][4 b], pre-set 0x40
  int bid = blockIdx.x;
  int dir = bid >> 4;
  int w   = bid & 15;
  int j0  = w << 4;
  int tid = threadIdx.x;
  int kc  = tid & 15;
  int r   = tid >> 4;                   // local gate row 0..63 (q = r>>4, jj = r&15)
  int grow = ((r>>4)<<8) + j0 + (r&15); // gate row in [0,1024)

  // W_hh slice: 16 floats per thread
  float wreg[16];
  {
    const f4* wp4 = (const f4*)(whh + (size_t)(dir*1024 + grow)*256 + (kc<<4));
    f4 v0 = wp4[0], v1 = wp4[1], v2 = wp4[2], v3 = wp4[3];
    #pragma unroll
    for (int i=0;i<4;i++){ wreg[i]=v0[i]; wreg[4+i]=v1[i]; wreg[8+i]=v2[i]; wreg[12+i]=v3[i]; }
  }

  __shared__ float hist[16384];                       // h history: [s][b*16+j2]
  __shared__ __attribute__((aligned(16))) float h_swz[2072];  // swizzled [k]{b0..3}
  __shared__ __attribute__((aligned(16))) f4 glds4[64];       // gate sums [r]{b0..3}

  for (int i = tid; i < 2072; i += 1024) h_swz[i] = 0.0f;
  __syncthreads();

  float* hb = hbuf + dir*4096;
  float c_reg = 0.0f;
  const float sent = __uint_as_float(0x40404040u);    // 3.004f, unreachable by |h|<1

  // poll/stage assignment: this thread owns buffer word 'tid' = (k = tid>>2, b = tid&3)
  int ldst = hswz(tid>>2) + (tid&3);

  for (int s = 0; s < 256; s++){
    int t = dir ? 255-s : s;
    // gx prefetch for the nonlinearity lanes (issued early, hidden under poll+dot)
    float gxv0=0.f, gxv1=0.f, gxv2=0.f, gxv3=0.f;
    if (tid < 64){
      int b = tid>>4, j2 = tid&15;
      const float* gp = gx + (size_t)((b<<8) + t)*2048 + dir*1024 + j0 + j2;
      gxv0 = gp[0]; gxv1 = gp[256]; gxv2 = gp[512]; gxv3 = gp[768];
    }
    if (s){
      // distributed poll: 1 dword per lane, sc0 sc1 (straight from coherence point)
      const float* pp = hb + (((s-1)&3)<<10) + tid;
      float v;
      for(;;){
        asm volatile("global_load_dword %0, %1, off sc0 sc1\n\ts_waitcnt vmcnt(0)"
                     : "=v"(v) : "v"(pp) : "memory");
        if (__all(v < 2.0f)) break;   // h < 1 < 2 < sentinel
      }
      h_swz[ldst] = v;                // stage to LDS once
    }
    __syncthreads();                  // bar1: staging complete
    // dot: acc[b] = sum_k W[grow][k] * h[k][b] over k in [16kc,16kc+16)
    float a0=0.f, a1=0.f, a2=0.f, a3=0.f;
    {
      int base = (kc<<7) + ((kc&7)<<2);   // hswz(16*kc)
      #pragma unroll
      for (int kk=0; kk<16; kk++){
        f4 h4 = *(const f4*)&h_swz[base + (kk<<3)];
        float wv = wreg[kk];
        a0 = fmaf(wv, h4[0], a0);
        a1 = fmaf(wv, h4[1], a1);
        a2 = fmaf(wv, h4[2], a2);
        a3 = fmaf(wv, h4[3], a3);
      }
    }
    // 16-lane butterfly reduce, pure VALU (DPP), no DS ops
    DPPRED16(a0); DPPRED16(a1); DPPRED16(a2); DPPRED16(a3);
    if (kc == 0) glds4[r] = (f4){a0, a1, a2, a3};
    __syncthreads();                  // bar2: gate sums visible
    if (tid < 64){                    // wave 0: nonlinearity + publish (+ lazy reset)
      int b = tid>>4, j2 = tid&15;
      const float* gl = (const float*)glds4;
      float gi = gxv0 + gl[(( 0+j2)<<2) + b];
      float gf = gxv1 + gl[((16+j2)<<2) + b];
      float gg = gxv2 + gl[((32+j2)<<2) + b];
      float go = gxv3 + gl[((48+j2)<<2) + b];
      c_reg   = sigf(gf)*c_reg + sigf(gi)*tanhf_fast(gg);
      float h = sigf(go)*tanhf_fast(c_reg);
      hist[(s<<6) + tid] = h;
      float* dst = hb + ((s&3)<<10) + ((j0+j2)<<2) + b;
      asm volatile("global_store_dword %[p], %[v], off sc0 sc1"
                   :: [p]"v"(dst), [v]"v"(h) : "memory");
      if (s >= 2){
        float* rst = hb + (((s-2)&3)<<10) + ((j0+j2)<<2) + b;
        asm volatile("global_store_dword %[p], %[v], off sc0 sc1"
                     :: [p]"v"(rst), [v]"v"(sent) : "memory");
      }
    }
    // no trailing barrier: next step's staging is gated by the global data itself
  }
  __syncthreads();
  // dump h history to hcat (once)
  for (int i = tid; i < 16384; i += 1024){
    int s = i>>6, lane = i&63, b = lane>>4, j2 = lane&15;
    int t = dir ? 255-s : s;
    hcat[(size_t)((b<<8)+t)*512 + (dir<<8) + j0 + j2] = hist[i];
  }
}

// ---------------- fused additive attention + softmax + ctx + classifier ----------------
__global__ __launch_bounds__(256) void k_attn(
    const float* __restrict__ q, const float* __restrict__ kmat,
    const float* __restrict__ h, const float* __restrict__ v,
    const float* __restrict__ clsW, const float* __restrict__ clsb,
    float* __restrict__ out){
  int bt = blockIdx.x;           // b*256 + t
  int b  = bt >> 8;
  int tid = threadIdx.x;
  __shared__ float q_s[512], v_s[512], p_s[256], red[8], ctx_s[512], part[240];
  *(float2*)&q_s[tid<<1] = *(const float2*)&q[(size_t)bt*512 + (tid<<1)];
  *(float2*)&v_s[tid<<1] = *(const float2*)&v[tid<<1];
  __syncthreads();
  const float* kp = kmat + (size_t)((b<<8) + tid)*512;
  float sc = 0.f;
  for (int d=0; d<512; d+=4){
    float4 kv = *(const float4*)&kp[d];
    sc += v_s[d+0]*tanhf_fast(q_s[d+0]+kv.x)
        + v_s[d+1]*tanhf_fast(q_s[d+1]+kv.y)
        + v_s[d+2]*tanhf_fast(q_s[d+2]+kv.z)
        + v_s[d+3]*tanhf_fast(q_s[d+3]+kv.w);
  }
  int wv = tid>>6, lane = tid&63;
  float m = sc;
  #pragma unroll
  for (int o=1;o<64;o<<=1) m = fmaxf(m, __shfl_xor(m,o,64));
  if (lane==0) red[wv] = m;
  __syncthreads();
  m = fmaxf(fmaxf(red[0],red[1]), fmaxf(red[2],red[3]));
  float p = __expf(sc - m);
  p_s[tid] = p;
  float sum = p;
  #pragma unroll
  for (int o=1;o<64;o<<=1) sum += __shfl_xor(sum,o,64);
  if (lane==0) red[4+wv] = sum;
  __syncthreads();
  float inv = 1.0f/(red[4]+red[5]+red[6]+red[7]);
  float cx=0.f, cy=0.f;
  for (int s2=0; s2<256; s2++){
    float pw = p_s[s2];
    float2 hv = *(const float2*)&h[(size_t)((b<<8)+s2)*512 + (tid<<1)];
    cx = fmaf(pw, hv.x, cx); cy = fmaf(pw, hv.y, cy);
  }
  ctx_s[tid<<1] = cx*inv; ctx_s[(tid<<1)+1] = cy*inv;
  __syncthreads();
  if (tid < 240){
    int c = tid>>4, ch = tid&15;
    const float* wrow = clsW + (size_t)c*512 + (ch<<5);
    const float* cc = &ctx_s[ch<<5];
    float acc = 0.f;
    #pragma unroll
    for (int i=0;i<32;i++) acc = fmaf(wrow[i], cc[i], acc);
    part[tid] = acc;
  }
  __syncthreads();
  if (tid < 15){
    float o = clsb[tid];
    #pragma unroll
    for (int i=0;i<16;i++) o += part[(tid<<4)+i];
    out[(size_t)bt*15 + tid] = o;
  }
}

extern "C" void kernel_launch(void* const* d_in, const int* in_sizes, int n_in,
                              void* d_out, int out_size, void* d_ws, size_t ws_size,
                              hipStream_t stream){
  (void)in_sizes; (void)n_in; (void)out_size; (void)ws_size;
  const int*   ids    = (const int*)  d_in[0];
  const float* emb    = (const float*)d_in[1];
  const float* w_ih0  = (const float*)d_in[2];
  const float* w_hh0  = (const float*)d_in[3];
  const float* b0     = (const float*)d_in[4];
  const float* w_ih   = (const float*)d_in[5];
  const float* w_hh   = (const float*)d_in[6];
  const float* b      = (const float*)d_in[7];
  const float* attn_W = (const float*)d_in[8];
  const float* attn_U = (const float*)d_in[9];
  const float* attn_v = (const float*)d_in[10];
  const float* cls_W  = (const float*)d_in[11];
  const float* cls_b  = (const float*)d_in[12];
  float* out = (float*)d_out;

  float* ws   = (float*)d_ws;
  float* x    = ws;                  // 131072
  float* gx   = x  + 131072;         // 2097152 (1024 x 2048)
  float* hA   = gx + 2097152;        // 524288  (1024 x 512)
  float* hB   = hA + 524288;         // 524288
  float* hbuf = hB + 524288;         // 3 layers x 8192 floats ([2][4][256][4])
  float* qb   = gx;                  // reuse gx after recurrences done
  float* kb   = gx + 524288;

  // sentinel-fill the h exchange buffers (0x40404040 = 3.004f, unreachable by |h|<=1)
  hipMemsetAsync(hbuf, 0x40, 3*8192*sizeof(float), stream);
  k_embed<<<512, 256, 0, stream>>>(ids, emb, x);

  dim3 gBig(16, 32);   // M=1024, N=2048
  dim3 gQK(16, 8);     // M=1024, N=512

  // layer 0
  k_gemm_bias<<<gBig, 256, 0, stream>>>(x, w_ih0, b0, gx, 2048, 128);
  k_lstm<<<32, 1024, 0, stream>>>(gx, w_hh0, hA, hbuf + 0*8192);
  // layer 1
  k_gemm_bias<<<gBig, 256, 0, stream>>>(hA, w_ih, b, gx, 2048, 512);
  k_lstm<<<32, 1024, 0, stream>>>(gx, w_hh, hB, hbuf + 1*8192);
  // layer 2
  k_gemm_bias<<<gBig, 256, 0, stream>>>(hB, w_ih + 2048*512, b + 2048, gx, 2048, 512);
  k_lstm<<<32, 1024, 0, stream>>>(gx, w_hh + 2048*256, hA, hbuf + 2*8192);
  // attention projections
  k_gemm_bias<<<gQK, 256, 0, stream>>>(hA, attn_W, nullptr, qb, 512, 512);
  k_gemm_bias<<<gQK, 256, 0, stream>>>(hA, attn_U, nullptr, kb, 512, 512);
  // fused scores/softmax/ctx/classifier
  k_attn<<<1024, 256, 0, stream>>>(qb, kb, hA, attn_v, cls_W, cls_b, out);
}